// Round 3
// baseline (72.553 us; speedup 1.0000x reference)
//
#include <hip/hip_runtime.h>

// TopKRouter: x[B=16,C=768,H=64,W=64] fp32, W[E=16,C=768], b[E=16], k=2.
// Two-phase: (1) C-split partial logits -> ws, (2) reduce+softmax+top2.
// Outputs concatenated fp32: topk_probs[16,2,64,64] | topk_indices[16,2,64,64]
// (as float) | scores[16,16,64,64].
//
// R3: phase-1 uses float2 (2 pixels/thread) -> 1024 blocks (16 waves/CU)
// instead of float4/512 blocks (8 waves/CU); acc = 32 VGPR leaves room for a
// deep load pipeline (unroll 16).

#define C_DIM 768
#define E_DIM 16
#define HW    4096   // 64*64
#define NPIX  65536  // 16*4096

// ---------------- Phase 1: partial logits over a channel segment ----------
// blockIdx.x -> pixel group (128 blocks x 256 thr x 2 pix = 65536)
// blockIdx.y -> channel segment (CL channels each)
template <int CL>
__global__ __launch_bounds__(256) void router_partial(
    const float* __restrict__ x,   // [B, C, HW]
    const float* __restrict__ Wm,  // [E, C]
    float* __restrict__ ws)        // [CS, E, NPIX] partial logits
{
    const int seg = blockIdx.y;
    const int c0  = seg * CL;
    const int pg  = (blockIdx.x * 256 + threadIdx.x) * 2;  // first pixel
    const int b   = pg >> 12;                              // block-uniform
    const int p   = pg & 4095;
    const float* xp = x + (size_t)b * C_DIM * HW + p;

    float2 acc[E_DIM];
#pragma unroll
    for (int e = 0; e < E_DIM; ++e) acc[e] = make_float2(0.f, 0.f);

#pragma unroll 16
    for (int c = c0; c < c0 + CL; ++c) {
        const float2 xv = *reinterpret_cast<const float2*>(xp + (size_t)c * HW);
#pragma unroll
        for (int e = 0; e < E_DIM; ++e) {
            const float w = Wm[e * C_DIM + c];  // wave-uniform -> SGPR
            acc[e].x = fmaf(xv.x, w, acc[e].x);
            acc[e].y = fmaf(xv.y, w, acc[e].y);
        }
    }

#pragma unroll
    for (int e = 0; e < E_DIM; ++e)
        *reinterpret_cast<float2*>(ws + (size_t)(seg * E_DIM + e) * NPIX + pg) = acc[e];
}

// ---------------- Phase 2: reduce segments + bias + softmax + top2 --------
template <int CS>
__global__ __launch_bounds__(256) void router_finish(
    const float* __restrict__ ws,    // [CS, E, NPIX]
    const float* __restrict__ bias,  // [E]
    float* __restrict__ out)
{
    const int g = blockIdx.x * 256 + threadIdx.x;  // pixel id
    const int b = g >> 12;
    const int p = g & 4095;

    float lg[E_DIM];
#pragma unroll
    for (int e = 0; e < E_DIM; ++e) lg[e] = bias[e];
#pragma unroll
    for (int s = 0; s < CS; ++s)
#pragma unroll
        for (int e = 0; e < E_DIM; ++e)
            lg[e] += ws[(size_t)(s * E_DIM + e) * NPIX + g];

    float m = -INFINITY;
#pragma unroll
    for (int e = 0; e < E_DIM; ++e) m = fmaxf(m, lg[e]);
    float pr[E_DIM];
    float sum = 0.0f;
#pragma unroll
    for (int e = 0; e < E_DIM; ++e) {
        pr[e] = __expf(lg[e] - m);
        sum += pr[e];
    }
    const float inv = 1.0f / sum;

    float* scores = out + 262144;
#pragma unroll
    for (int e = 0; e < E_DIM; ++e) {
        const float s = pr[e] * inv;
        pr[e] = s;
        scores[(size_t)(b * E_DIM + e) * HW + p] = s;
    }

    // top-2, ties -> lower index (matches jax.lax.top_k)
    int i1 = 0;
    float p1 = pr[0];
#pragma unroll
    for (int e = 1; e < E_DIM; ++e)
        if (pr[e] > p1) { p1 = pr[e]; i1 = e; }
    int i2 = -1;
    float p2 = -INFINITY;
#pragma unroll
    for (int e = 0; e < E_DIM; ++e)
        if (e != i1 && pr[e] > p2) { p2 = pr[e]; i2 = e; }

    const float rs = 1.0f / (p1 + p2);
    const size_t o1 = (size_t)(b * 2 + 0) * HW + p;
    const size_t o2 = (size_t)(b * 2 + 1) * HW + p;
    out[o1] = p1 * rs;
    out[o2] = p2 * rs;
    float* idxo = out + 131072;
    idxo[o1] = (float)i1;
    idxo[o2] = (float)i2;
}

// ---------------- Fallback: fused single-pass (if ws too small) -----------
__global__ __launch_bounds__(256) void topk_router_fused(
    const float* __restrict__ x, const float* __restrict__ Wm,
    const float* __restrict__ bias, float* __restrict__ out)
{
    const int g = blockIdx.x * 256 + threadIdx.x;
    const int b = g >> 12;
    const int p = g & 4095;
    const float* xp = x + (size_t)b * C_DIM * HW + p;

    float acc[E_DIM];
#pragma unroll
    for (int e = 0; e < E_DIM; ++e) acc[e] = 0.0f;
#pragma unroll 16
    for (int c = 0; c < C_DIM; ++c) {
        const float xv = xp[(size_t)c * HW];
#pragma unroll
        for (int e = 0; e < E_DIM; ++e)
            acc[e] = fmaf(xv, Wm[e * C_DIM + c], acc[e]);
    }
    float m = -INFINITY;
#pragma unroll
    for (int e = 0; e < E_DIM; ++e) { acc[e] += bias[e]; m = fmaxf(m, acc[e]); }
    float pr[E_DIM]; float sum = 0.0f;
#pragma unroll
    for (int e = 0; e < E_DIM; ++e) { pr[e] = __expf(acc[e] - m); sum += pr[e]; }
    const float inv = 1.0f / sum;
    float* scores = out + 262144;
#pragma unroll
    for (int e = 0; e < E_DIM; ++e) {
        const float s = pr[e] * inv; pr[e] = s;
        scores[(size_t)(b * E_DIM + e) * HW + p] = s;
    }
    int i1 = 0; float p1 = pr[0];
#pragma unroll
    for (int e = 1; e < E_DIM; ++e) if (pr[e] > p1) { p1 = pr[e]; i1 = e; }
    int i2 = -1; float p2 = -INFINITY;
#pragma unroll
    for (int e = 0; e < E_DIM; ++e) if (e != i1 && pr[e] > p2) { p2 = pr[e]; i2 = e; }
    const float rs = 1.0f / (p1 + p2);
    const size_t o1 = (size_t)(b * 2 + 0) * HW + p;
    const size_t o2 = (size_t)(b * 2 + 1) * HW + p;
    out[o1] = p1 * rs; out[o2] = p2 * rs;
    float* idxo = out + 131072;
    idxo[o1] = (float)i1; idxo[o2] = (float)i2;
}

extern "C" void kernel_launch(void* const* d_in, const int* in_sizes, int n_in,
                              void* d_out, int out_size, void* d_ws, size_t ws_size,
                              hipStream_t stream) {
    const float* x  = (const float*)d_in[0];
    const float* Wm = (const float*)d_in[1];
    const float* bs = (const float*)d_in[2];
    float* out = (float*)d_out;
    float* ws  = (float*)d_ws;

    const size_t seg_bytes = (size_t)E_DIM * NPIX * sizeof(float);  // 4 MB

    if (ws_size >= 8 * seg_bytes) {
        router_partial<96><<<dim3(128, 8), 256, 0, stream>>>(x, Wm, ws);
        router_finish<8><<<NPIX / 256, 256, 0, stream>>>(ws, bs, out);
    } else if (ws_size >= 4 * seg_bytes) {
        router_partial<192><<<dim3(128, 4), 256, 0, stream>>>(x, Wm, ws);
        router_finish<4><<<NPIX / 256, 256, 0, stream>>>(ws, bs, out);
    } else if (ws_size >= 2 * seg_bytes) {
        router_partial<384><<<dim3(128, 2), 256, 0, stream>>>(x, Wm, ws);
        router_finish<2><<<NPIX / 256, 256, 0, stream>>>(ws, bs, out);
    } else if (ws_size >= seg_bytes) {
        router_partial<768><<<dim3(128, 1), 256, 0, stream>>>(x, Wm, ws);
        router_finish<1><<<NPIX / 256, 256, 0, stream>>>(ws, bs, out);
    } else {
        topk_router_fused<<<NPIX / 256, 256, 0, stream>>>(x, Wm, bs, out);
    }
}

// Round 4
// 41.321 us; speedup vs baseline: 1.7559x; 1.7559x over previous
//
#include <hip/hip_runtime.h>

// TopKRouter: x[B=16,C=768,H=64,W=64] fp32, W[E=16,C=768], b[E=16], k=2.
// R4: single fused kernel. Key fix: W transposed to Wt[C][E] (prologue kernel,
// 48 KB in ws) so the 16 per-channel weights are ONE contiguous 64 B
// wave-uniform load (s_load stream) instead of 16 scattered 3KB-apart scalar
// loads (the diagnosed per-channel lgkmcnt stall in R1-R3).
// Block = 128 pixels x 4 channel-groups (192 ch each); LDS reduce; epilogue
// softmax+top2 by threads 0..127.
// Outputs fp32 concat: topk_probs[16,2,64,64] | topk_indices[16,2,64,64] |
// scores[16,16,64,64].

#define C_DIM 768
#define E_DIM 16
#define HW    4096   // 64*64
#define NPIX  65536  // 16*4096

// ---------------- Prologue: Wt[c][e] = W[e][c] ----------------------------
__global__ __launch_bounds__(256) void transpose_w(
    const float* __restrict__ Wm, float* __restrict__ Wt)
{
    const int t = blockIdx.x * 256 + threadIdx.x;  // 12288 elements
    if (t < C_DIM * E_DIM) {
        const int c = t >> 4, e = t & 15;
        Wt[t] = Wm[e * C_DIM + c];
    }
}

// ---------------- Fused main ----------------------------------------------
__global__ __launch_bounds__(256) void router_main(
    const float* __restrict__ x,     // [B, C, HW]
    const float* __restrict__ Wt,    // [C, E] transposed weights (in ws)
    const float* __restrict__ bias,  // [E]
    float* __restrict__ out)
{
    __shared__ float lds[4][128][17];  // [cg][px][e] padded: reads conflict-free

    const int p0  = blockIdx.x * 128;            // first pixel of block
    const int b   = p0 >> 12;                    // batch (block-uniform)
    const int pb  = p0 & 4095;
    const int cg  = __builtin_amdgcn_readfirstlane(threadIdx.x >> 6);
    const int px2 = threadIdx.x & 63;            // lane -> pixel pair
    const int c0  = cg * 192;

    const float* xp = x + (size_t)b * C_DIM * HW + pb + 2 * px2;

    float2 acc[E_DIM];
#pragma unroll
    for (int e = 0; e < E_DIM; ++e) acc[e] = make_float2(0.f, 0.f);

#pragma unroll 4
    for (int c = c0; c < c0 + 192; ++c) {
        const float2 xv = *reinterpret_cast<const float2*>(xp + (size_t)c * HW);
        const float4* wt = reinterpret_cast<const float4*>(Wt + c * E_DIM);
        const float4 w0 = wt[0], w1 = wt[1], w2 = wt[2], w3 = wt[3];
        acc[ 0].x = fmaf(xv.x, w0.x, acc[ 0].x); acc[ 0].y = fmaf(xv.y, w0.x, acc[ 0].y);
        acc[ 1].x = fmaf(xv.x, w0.y, acc[ 1].x); acc[ 1].y = fmaf(xv.y, w0.y, acc[ 1].y);
        acc[ 2].x = fmaf(xv.x, w0.z, acc[ 2].x); acc[ 2].y = fmaf(xv.y, w0.z, acc[ 2].y);
        acc[ 3].x = fmaf(xv.x, w0.w, acc[ 3].x); acc[ 3].y = fmaf(xv.y, w0.w, acc[ 3].y);
        acc[ 4].x = fmaf(xv.x, w1.x, acc[ 4].x); acc[ 4].y = fmaf(xv.y, w1.x, acc[ 4].y);
        acc[ 5].x = fmaf(xv.x, w1.y, acc[ 5].x); acc[ 5].y = fmaf(xv.y, w1.y, acc[ 5].y);
        acc[ 6].x = fmaf(xv.x, w1.z, acc[ 6].x); acc[ 6].y = fmaf(xv.y, w1.z, acc[ 6].y);
        acc[ 7].x = fmaf(xv.x, w1.w, acc[ 7].x); acc[ 7].y = fmaf(xv.y, w1.w, acc[ 7].y);
        acc[ 8].x = fmaf(xv.x, w2.x, acc[ 8].x); acc[ 8].y = fmaf(xv.y, w2.x, acc[ 8].y);
        acc[ 9].x = fmaf(xv.x, w2.y, acc[ 9].x); acc[ 9].y = fmaf(xv.y, w2.y, acc[ 9].y);
        acc[10].x = fmaf(xv.x, w2.z, acc[10].x); acc[10].y = fmaf(xv.y, w2.z, acc[10].y);
        acc[11].x = fmaf(xv.x, w2.w, acc[11].x); acc[11].y = fmaf(xv.y, w2.w, acc[11].y);
        acc[12].x = fmaf(xv.x, w3.x, acc[12].x); acc[12].y = fmaf(xv.y, w3.x, acc[12].y);
        acc[13].x = fmaf(xv.x, w3.y, acc[13].x); acc[13].y = fmaf(xv.y, w3.y, acc[13].y);
        acc[14].x = fmaf(xv.x, w3.z, acc[14].x); acc[14].y = fmaf(xv.y, w3.z, acc[14].y);
        acc[15].x = fmaf(xv.x, w3.w, acc[15].x); acc[15].y = fmaf(xv.y, w3.w, acc[15].y);
    }

    // stage partials: [cg][pixel][e]
#pragma unroll
    for (int e = 0; e < E_DIM; ++e) {
        lds[cg][2 * px2][e]     = acc[e].x;
        lds[cg][2 * px2 + 1][e] = acc[e].y;
    }
    __syncthreads();

    const int t = threadIdx.x;
    if (t < 128) {
        const int p = pb + t;  // pixel within b-plane

        float lg[E_DIM];
#pragma unroll
        for (int e = 0; e < E_DIM; ++e)
            lg[e] = bias[e] + lds[0][t][e] + lds[1][t][e] + lds[2][t][e] + lds[3][t][e];

        float m = -INFINITY;
#pragma unroll
        for (int e = 0; e < E_DIM; ++e) m = fmaxf(m, lg[e]);
        float pr[E_DIM];
        float sum = 0.0f;
#pragma unroll
        for (int e = 0; e < E_DIM; ++e) {
            pr[e] = __expf(lg[e] - m);
            sum += pr[e];
        }
        const float inv = 1.0f / sum;

        float* scores = out + 262144;
#pragma unroll
        for (int e = 0; e < E_DIM; ++e) {
            const float s = pr[e] * inv;
            pr[e] = s;
            scores[(size_t)(b * E_DIM + e) * HW + p] = s;
        }

        // top-2, ties -> lower index (matches jax.lax.top_k)
        int i1 = 0;
        float p1 = pr[0];
#pragma unroll
        for (int e = 1; e < E_DIM; ++e)
            if (pr[e] > p1) { p1 = pr[e]; i1 = e; }
        int i2 = -1;
        float p2 = -INFINITY;
#pragma unroll
        for (int e = 0; e < E_DIM; ++e)
            if (e != i1 && pr[e] > p2) { p2 = pr[e]; i2 = e; }

        const float rs = 1.0f / (p1 + p2);
        const size_t o1 = (size_t)(b * 2 + 0) * HW + p;
        const size_t o2 = (size_t)(b * 2 + 1) * HW + p;
        out[o1] = p1 * rs;
        out[o2] = p2 * rs;
        float* idxo = out + 131072;
        idxo[o1] = (float)i1;
        idxo[o2] = (float)i2;
    }
}

// ---------------- Fallback: fused single-pass, no ws ----------------------
__global__ __launch_bounds__(256) void topk_router_fused(
    const float* __restrict__ x, const float* __restrict__ Wm,
    const float* __restrict__ bias, float* __restrict__ out)
{
    const int g = blockIdx.x * 256 + threadIdx.x;
    const int b = g >> 12;
    const int p = g & 4095;
    const float* xp = x + (size_t)b * C_DIM * HW + p;

    float acc[E_DIM];
#pragma unroll
    for (int e = 0; e < E_DIM; ++e) acc[e] = 0.0f;
#pragma unroll 16
    for (int c = 0; c < C_DIM; ++c) {
        const float xv = xp[(size_t)c * HW];
#pragma unroll
        for (int e = 0; e < E_DIM; ++e)
            acc[e] = fmaf(xv, Wm[e * C_DIM + c], acc[e]);
    }
    float m = -INFINITY;
#pragma unroll
    for (int e = 0; e < E_DIM; ++e) { acc[e] += bias[e]; m = fmaxf(m, acc[e]); }
    float pr[E_DIM]; float sum = 0.0f;
#pragma unroll
    for (int e = 0; e < E_DIM; ++e) { pr[e] = __expf(acc[e] - m); sum += pr[e]; }
    const float inv = 1.0f / sum;
    float* scores = out + 262144;
#pragma unroll
    for (int e = 0; e < E_DIM; ++e) {
        const float s = pr[e] * inv; pr[e] = s;
        scores[(size_t)(b * E_DIM + e) * HW + p] = s;
    }
    int i1 = 0; float p1 = pr[0];
#pragma unroll
    for (int e = 1; e < E_DIM; ++e) if (pr[e] > p1) { p1 = pr[e]; i1 = e; }
    int i2 = -1; float p2 = -INFINITY;
#pragma unroll
    for (int e = 0; e < E_DIM; ++e) if (e != i1 && pr[e] > p2) { p2 = pr[e]; i2 = e; }
    const float rs = 1.0f / (p1 + p2);
    const size_t o1 = (size_t)(b * 2 + 0) * HW + p;
    const size_t o2 = (size_t)(b * 2 + 1) * HW + p;
    out[o1] = p1 * rs; out[o2] = p2 * rs;
    float* idxo = out + 131072;
    idxo[o1] = (float)i1; idxo[o2] = (float)i2;
}

extern "C" void kernel_launch(void* const* d_in, const int* in_sizes, int n_in,
                              void* d_out, int out_size, void* d_ws, size_t ws_size,
                              hipStream_t stream) {
    const float* x  = (const float*)d_in[0];
    const float* Wm = (const float*)d_in[1];
    const float* bs = (const float*)d_in[2];
    float* out = (float*)d_out;
    float* Wt  = (float*)d_ws;  // 48 KB

    if (ws_size >= (size_t)C_DIM * E_DIM * sizeof(float)) {
        transpose_w<<<48, 256, 0, stream>>>(Wm, Wt);
        router_main<<<NPIX / 128, 256, 0, stream>>>(x, Wt, bs, out);
    } else {
        topk_router_fused<<<NPIX / 256, 256, 0, stream>>>(x, Wm, bs, out);
    }
}